// Round 21
// baseline (30.922 us; speedup 1.0000x reference)
//
#include <hip/hip_runtime.h>

// Problem constants
#define NSPLIT  100
#define MTREE   20
#define MAXLEAF 64
#define EMB     32
#define NTREES  2000
#define BATCH   4096
#define OUTW    (NSPLIT*EMB)            // 3200
#define SPLIT_B 81920                   // bf16 table bytes per split

#define THREADS 1024
#define CHUNKS  8                       // batch-chunks per split
#define BPC     (BATCH/CHUNKS)          // 512 batches/block, 2 per group
#define NBLK    (NSPLIT*CHUNKS)         // 800

// v21 = v20 (29.9us) with the staging loop at FULL depth.
// v20 inherited "#pragma unroll 2" from v7's 64-reg spill discipline -> only
// 2 f32 loads in flight; staging = 5 serial L2 round-trips (~1.5-2.5K cyc)
// before the barrier. v20's VGPR_Count=36 vs a 128 cap (occupancy is
// LDS-bound at 2 blocks/CU up to 128 regs) -> room for 10-deep. Staging is
// restructured load-all-10 -> cvt/write-all-10 (named regs, no interleaved
// consume) so all 10 global_load_dwordx4 stay outstanding.
// Gather body, geometry, dot2, single barrier: byte-identical to v20.
__device__ __forceinline__ unsigned int pk_bf16(float a, float b) {
    unsigned int r;
    asm("v_cvt_pk_bf16_f32 %0, %1, %2" : "=v"(r) : "v"(a), "v"(b));
    return r;
}

// a += 1.0 * (selected bf16 half of w): one VOP3P dot2.
__device__ __forceinline__ void d2(float& a, unsigned int w, unsigned int sel) {
    asm("v_dot2_f32_bf16 %0, %1, %2, %0" : "+v"(a) : "v"(w), "v"(sel));
}

__global__ __launch_bounds__(THREADS, 1) void leaf2emb_v21(
    const int* __restrict__ leaves,     // [BATCH, NTREES]
    const float* __restrict__ embed,    // [NSPLIT, MTREE*MAXLEAF, EMB] f32
    float* __restrict__ out)            // [BATCH, OUTW]
{
    __shared__ char tl[SPLIT_B];        // 80 KiB: whole split table, bf16

    // XCD-chunked swizzle: 800 = 8 x 100 -> a split's 8 blocks share an XCD;
    // its 1.6 MB f32 slice stays L2-resident across the 8 re-reads.
    const int bid = blockIdx.x;
    const int wkr = (bid & 7) * (NBLK / 8) + (bid >> 3);
    const int s     = wkr >> 3;
    const int chunk = wkr & 7;

    const int tid = threadIdx.x;
    const int l   = tid & 3;            // lane-in-group: dims [8l, 8l+8)
    const int g   = tid >> 2;           // group id (256 groups, 2 batches each)

    // ---- fused staging: 10 loads ALL in flight, then cvt+write burst ----
    {
        const float4* emb4 = (const float4*)embed + (size_t)s * 10240;
        const float4 t0 = emb4[tid];
        const float4 t1 = emb4[tid + 1024];
        const float4 t2 = emb4[tid + 2048];
        const float4 t3 = emb4[tid + 3072];
        const float4 t4 = emb4[tid + 4096];
        const float4 t5 = emb4[tid + 5120];
        const float4 t6 = emb4[tid + 6144];
        const float4 t7 = emb4[tid + 7168];
        const float4 t8 = emb4[tid + 8192];
        const float4 t9 = emb4[tid + 9216];
        uint2* tw = (uint2*)tl + tid;
        tw[0]        = make_uint2(pk_bf16(t0.x, t0.y), pk_bf16(t0.z, t0.w));
        tw[1024]     = make_uint2(pk_bf16(t1.x, t1.y), pk_bf16(t1.z, t1.w));
        tw[2048]     = make_uint2(pk_bf16(t2.x, t2.y), pk_bf16(t2.z, t2.w));
        tw[3072]     = make_uint2(pk_bf16(t3.x, t3.y), pk_bf16(t3.z, t3.w));
        tw[4096]     = make_uint2(pk_bf16(t4.x, t4.y), pk_bf16(t4.z, t4.w));
        tw[5120]     = make_uint2(pk_bf16(t5.x, t5.y), pk_bf16(t5.z, t5.w));
        tw[6144]     = make_uint2(pk_bf16(t6.x, t6.y), pk_bf16(t6.z, t6.w));
        tw[7168]     = make_uint2(pk_bf16(t7.x, t7.y), pk_bf16(t7.z, t7.w));
        tw[8192]     = make_uint2(pk_bf16(t8.x, t8.y), pk_bf16(t8.z, t8.w));
        tw[9216]     = make_uint2(pk_bf16(t9.x, t9.y), pk_bf16(t9.z, t9.w));
    }

    const int bA = chunk * BPC + g;
    const int bB = bA + 256;
    const int4* lvA = (const int4*)(leaves + (size_t)bA * NTREES + s * MTREE);
    const int4* lvB = (const int4*)(leaves + (size_t)bB * NTREES + s * MTREE);

    // batch-A leaves in flight during the staging tail
    int4 L0 = lvA[0], L1 = lvA[1], L2 = lvA[2], L3 = lvA[3], L4 = lvA[4];

    __syncthreads();                    // the kernel's ONLY barrier

    const char* tb  = tl + l * 16;
    const char* tbH = tb + 65536;       // trees 16..19 window (ds imm < 64K)

    const unsigned int selL = 0x00003F80u;   // {hi=0, lo=1.0bf16}
    const unsigned int selH = 0x3F800000u;   // {hi=1.0bf16, lo=0}

#define ROWL(T, LEAF) (*(const uint4*)(tb  + (T) * 4096 + ((LEAF) << 6)))
#define ROWH(T, LEAF) (*(const uint4*)(tbH + ((T) - 16) * 4096 + ((LEAF) << 6)))
#define D2ACC(V) { \
        d2(a0.x, (V).x, selL); d2(a0.y, (V).x, selH); \
        d2(a0.z, (V).y, selL); d2(a0.w, (V).y, selH); \
        d2(a1.x, (V).z, selL); d2(a1.y, (V).z, selH); \
        d2(a1.z, (V).w, selL); d2(a1.w, (V).w, selH); }

    float4 a0 = {0,0,0,0}, a1 = {0,0,0,0};

    // ---- batch A: 16 reads issued up front, B-leaves load under consume ----
    uint4 v00 = ROWL(0,  L0.x), v01 = ROWL(1,  L0.y), v02 = ROWL(2,  L0.z), v03 = ROWL(3,  L0.w);
    uint4 v04 = ROWL(4,  L1.x), v05 = ROWL(5,  L1.y), v06 = ROWL(6,  L1.z), v07 = ROWL(7,  L1.w);
    uint4 v08 = ROWL(8,  L2.x), v09 = ROWL(9,  L2.y), v10 = ROWL(10, L2.z), v11 = ROWL(11, L2.w);
    uint4 v12 = ROWL(12, L3.x), v13 = ROWL(13, L3.y), v14 = ROWL(14, L3.z), v15 = ROWL(15, L3.w);
    uint4 v16 = ROWH(16, L4.x), v17 = ROWH(17, L4.y), v18 = ROWH(18, L4.z), v19 = ROWH(19, L4.w);
    int4 M0 = lvB[0], M1 = lvB[1], M2 = lvB[2], M3 = lvB[3], M4 = lvB[4];
    D2ACC(v00) D2ACC(v01) D2ACC(v02) D2ACC(v03)
    D2ACC(v04) D2ACC(v05) D2ACC(v06) D2ACC(v07)
    D2ACC(v08) D2ACC(v09) D2ACC(v10) D2ACC(v11)
    D2ACC(v12) D2ACC(v13) D2ACC(v14) D2ACC(v15)
    D2ACC(v16) D2ACC(v17) D2ACC(v18) D2ACC(v19)
    {
        float* oA = out + (size_t)bA * OUTW + s * EMB + l * 8;
        *(float4*)(oA)     = a0;
        *(float4*)(oA + 4) = a1;
    }

    // ---- batch B ----
    a0 = make_float4(0, 0, 0, 0);
    a1 = make_float4(0, 0, 0, 0);
    v00 = ROWL(0,  M0.x); v01 = ROWL(1,  M0.y); v02 = ROWL(2,  M0.z); v03 = ROWL(3,  M0.w);
    v04 = ROWL(4,  M1.x); v05 = ROWL(5,  M1.y); v06 = ROWL(6,  M1.z); v07 = ROWL(7,  M1.w);
    v08 = ROWL(8,  M2.x); v09 = ROWL(9,  M2.y); v10 = ROWL(10, M2.z); v11 = ROWL(11, M2.w);
    v12 = ROWL(12, M3.x); v13 = ROWL(13, M3.y); v14 = ROWL(14, M3.z); v15 = ROWL(15, M3.w);
    v16 = ROWH(16, M4.x); v17 = ROWH(17, M4.y); v18 = ROWH(18, M4.z); v19 = ROWH(19, M4.w);
    D2ACC(v00) D2ACC(v01) D2ACC(v02) D2ACC(v03)
    D2ACC(v04) D2ACC(v05) D2ACC(v06) D2ACC(v07)
    D2ACC(v08) D2ACC(v09) D2ACC(v10) D2ACC(v11)
    D2ACC(v12) D2ACC(v13) D2ACC(v14) D2ACC(v15)
    D2ACC(v16) D2ACC(v17) D2ACC(v18) D2ACC(v19)
    {
        float* oB = out + (size_t)bB * OUTW + s * EMB + l * 8;
        *(float4*)(oB)     = a0;
        *(float4*)(oB + 4) = a1;
    }

#undef ROWL
#undef ROWH
#undef D2ACC
}

extern "C" void kernel_launch(void* const* d_in, const int* in_sizes, int n_in,
                              void* d_out, int out_size, void* d_ws, size_t ws_size,
                              hipStream_t stream) {
    const int* leaves  = (const int*)d_in[0];
    const float* embed = (const float*)d_in[1];
    float* out         = (float*)d_out;

    leaf2emb_v21<<<dim3(NBLK), dim3(THREADS), 0, stream>>>(leaves, embed, out);
}

// Round 22
// 26.577 us; speedup vs baseline: 1.1635x; 1.1635x over previous
//
#include <hip/hip_runtime.h>

// Problem constants
#define NSPLIT  100
#define MTREE   20
#define MAXLEAF 64
#define EMB     32
#define NTREES  2000
#define BATCH   4096
#define OUTW    (NSPLIT*EMB)            // 3200
#define SPLIT_B 81920                   // bf16 table bytes per split

#define THREADS 1024
#define CHUNKS  4                       // batch-chunks per split
#define BPC     (BATCH/CHUNKS)          // 1024 batches/block, 4 per group
#define NBLK    (NSPLIT*CHUNKS)         // 400

// v22 = v20 (29.9us champion) with CHUNKS 8 -> 4: the one un-swept parameter
// of the fused-staging structure. Halves EVERY aggregate staging term (f32
// L2 reads 131->66 MB, cvt_pk and ds_write instruction counts halved) while
// gather work, streams, LDS (80 KiB, 2 blocks/CU), and the conflict profile
// stay identical. 400 blocks < 512 co-resident slots -> single dispatch
// wave, no partial second round. Each group does 4 batches sequentially,
// next batch's leaves loading under the current consume (v20's pattern x4;
// per-batch codegen identical -> same spill behavior expected).
// Pre-registered: neutral result => staging fully hidden => v20-family is
// the practical floor.
__device__ __forceinline__ unsigned int pk_bf16(float a, float b) {
    unsigned int r;
    asm("v_cvt_pk_bf16_f32 %0, %1, %2" : "=v"(r) : "v"(a), "v"(b));
    return r;
}

// a += 1.0 * (selected bf16 half of w): one VOP3P dot2.
__device__ __forceinline__ void d2(float& a, unsigned int w, unsigned int sel) {
    asm("v_dot2_f32_bf16 %0, %1, %2, %0" : "+v"(a) : "v"(w), "v"(sel));
}

__global__ __launch_bounds__(THREADS, 1) void leaf2emb_v22(
    const int* __restrict__ leaves,     // [BATCH, NTREES]
    const float* __restrict__ embed,    // [NSPLIT, MTREE*MAXLEAF, EMB] f32
    float* __restrict__ out)            // [BATCH, OUTW]
{
    __shared__ char tl[SPLIT_B];        // 80 KiB: whole split table, bf16

    // XCD-chunked swizzle: 400 = 8 x 50 -> a split's 4 blocks share an XCD;
    // its 1.6 MB f32 slice stays L2-resident across the 4 re-reads.
    const int bid = blockIdx.x;
    const int wkr = (bid & 7) * (NBLK / 8) + (bid >> 3);
    const int s     = wkr >> 2;
    const int chunk = wkr & 3;

    const int tid = threadIdx.x;
    const int l   = tid & 3;            // lane-in-group: dims [8l, 8l+8)
    const int g   = tid >> 2;           // group id (256 groups, 4 batches each)

    // ---- fused staging: f32 global -> cvt_pk -> LINEAR bf16 LDS ----
    // (v20's exact loop: unroll 2; full-depth variant was neutral, v21)
    {
        const float4* emb4 = (const float4*)embed + (size_t)s * 10240;
#pragma unroll 2
        for (int k = 0; k < 10; ++k) {
            const int i = tid + k * 1024;
            const float4 v = emb4[i];
            *(uint2*)(tl + i * 8) =
                make_uint2(pk_bf16(v.x, v.y), pk_bf16(v.z, v.w));
        }
    }

    const int b0 = chunk * BPC + g;     // batches b0, +256, +512, +768
    const int4* lv0 = (const int4*)(leaves + (size_t)b0 * NTREES + s * MTREE);
    const int4* lv1 = (const int4*)((const int*)lv0 + 256 * NTREES);
    const int4* lv2 = (const int4*)((const int*)lv0 + 512 * NTREES);
    const int4* lv3 = (const int4*)((const int*)lv0 + 768 * NTREES);

    // batch-0 leaves in flight during the staging tail
    int4 L0 = lv0[0], L1 = lv0[1], L2 = lv0[2], L3 = lv0[3], L4 = lv0[4];

    __syncthreads();                    // the kernel's ONLY barrier

    const char* tb  = tl + l * 16;
    const char* tbH = tb + 65536;       // trees 16..19 window (ds imm < 64K)

    const unsigned int selL = 0x00003F80u;   // {hi=0, lo=1.0bf16}
    const unsigned int selH = 0x3F800000u;   // {hi=1.0bf16, lo=0}

#define ROWL(T, LEAF) (*(const uint4*)(tb  + (T) * 4096 + ((LEAF) << 6)))
#define ROWH(T, LEAF) (*(const uint4*)(tbH + ((T) - 16) * 4096 + ((LEAF) << 6)))
#define D2ACC(V) { \
        d2(a0.x, (V).x, selL); d2(a0.y, (V).x, selH); \
        d2(a0.z, (V).y, selL); d2(a0.w, (V).y, selH); \
        d2(a1.x, (V).z, selL); d2(a1.y, (V).z, selH); \
        d2(a1.z, (V).w, selL); d2(a1.w, (V).w, selH); }

    // Issue 20 reads from P*, load NEXT batch's leaves into N* from NP (or
    // skip via NOP form), consume, write out batch BB. v20's proven pattern.
#define ISSUE(P0, P1, P2, P3, P4) \
    v00 = ROWL(0,(P0).x); v01 = ROWL(1,(P0).y); v02 = ROWL(2,(P0).z); v03 = ROWL(3,(P0).w); \
    v04 = ROWL(4,(P1).x); v05 = ROWL(5,(P1).y); v06 = ROWL(6,(P1).z); v07 = ROWL(7,(P1).w); \
    v08 = ROWL(8,(P2).x); v09 = ROWL(9,(P2).y); v10 = ROWL(10,(P2).z); v11 = ROWL(11,(P2).w); \
    v12 = ROWL(12,(P3).x); v13 = ROWL(13,(P3).y); v14 = ROWL(14,(P3).z); v15 = ROWL(15,(P3).w); \
    v16 = ROWH(16,(P4).x); v17 = ROWH(17,(P4).y); v18 = ROWH(18,(P4).z); v19 = ROWH(19,(P4).w);
#define CONSUME \
    D2ACC(v00) D2ACC(v01) D2ACC(v02) D2ACC(v03) \
    D2ACC(v04) D2ACC(v05) D2ACC(v06) D2ACC(v07) \
    D2ACC(v08) D2ACC(v09) D2ACC(v10) D2ACC(v11) \
    D2ACC(v12) D2ACC(v13) D2ACC(v14) D2ACC(v15) \
    D2ACC(v16) D2ACC(v17) D2ACC(v18) D2ACC(v19)
#define WRITEOUT(BB) { \
    float* o_ = out + (size_t)(BB) * OUTW + s * EMB + l * 8; \
    *(float4*)(o_)     = a0; \
    *(float4*)(o_ + 4) = a1; }

    uint4 v00, v01, v02, v03, v04, v05, v06, v07;
    uint4 v08, v09, v10, v11, v12, v13, v14, v15, v16, v17, v18, v19;
    float4 a0, a1;
    int4 M0, M1, M2, M3, M4;

    // ---- batch 0 (leaves L), batch-1 leaves load under consume ----
    a0 = make_float4(0,0,0,0); a1 = make_float4(0,0,0,0);
    ISSUE(L0, L1, L2, L3, L4)
    M0 = lv1[0]; M1 = lv1[1]; M2 = lv1[2]; M3 = lv1[3]; M4 = lv1[4];
    CONSUME
    WRITEOUT(b0)

    // ---- batch 1 (leaves M), batch-2 leaves load under consume ----
    a0 = make_float4(0,0,0,0); a1 = make_float4(0,0,0,0);
    ISSUE(M0, M1, M2, M3, M4)
    L0 = lv2[0]; L1 = lv2[1]; L2 = lv2[2]; L3 = lv2[3]; L4 = lv2[4];
    CONSUME
    WRITEOUT(b0 + 256)

    // ---- batch 2 (leaves L), batch-3 leaves load under consume ----
    a0 = make_float4(0,0,0,0); a1 = make_float4(0,0,0,0);
    ISSUE(L0, L1, L2, L3, L4)
    M0 = lv3[0]; M1 = lv3[1]; M2 = lv3[2]; M3 = lv3[3]; M4 = lv3[4];
    CONSUME
    WRITEOUT(b0 + 512)

    // ---- batch 3 (leaves M) ----
    a0 = make_float4(0,0,0,0); a1 = make_float4(0,0,0,0);
    ISSUE(M0, M1, M2, M3, M4)
    CONSUME
    WRITEOUT(b0 + 768)

#undef ROWL
#undef ROWH
#undef D2ACC
#undef ISSUE
#undef CONSUME
#undef WRITEOUT
}

extern "C" void kernel_launch(void* const* d_in, const int* in_sizes, int n_in,
                              void* d_out, int out_size, void* d_ws, size_t ws_size,
                              hipStream_t stream) {
    const int* leaves  = (const int*)d_in[0];
    const float* embed = (const float*)d_in[1];
    float* out         = (float*)d_out;

    leaf2emb_v22<<<dim3(NBLK), dim3(THREADS), 0, stream>>>(leaves, embed, out);
}